// Round 2
// baseline (445.224 us; speedup 1.0000x reference)
//
#include <hip/hip_runtime.h>

typedef __attribute__((ext_vector_type(8))) short s8;
typedef __attribute__((ext_vector_type(4))) short s4;
typedef __attribute__((ext_vector_type(4))) float f4;
typedef unsigned short u16;

__device__ __forceinline__ u16 f2bf(float f){
  union { float f; unsigned int i; } v; v.f = f;
  unsigned int x = v.i;
  return (u16)((x + 0x7fffu + ((x >> 16) & 1u)) >> 16);
}
__device__ __forceinline__ s8 ld8(const u16* p){
  return *reinterpret_cast<const s8*>(p);
}

#define MFMA16(a, b, c) __builtin_amdgcn_mfma_f32_16x16x32_bf16((a), (b), (c), 0, 0, 0)

// ---------------------------------------------------------------------------
// fp32 -> bf16 conversion of the three activation inputs (memory-bound).
// ---------------------------------------------------------------------------
__global__ __launch_bounds__(256) void cvt_x(
    const float* __restrict__ x0, const float* __restrict__ x1,
    const float* __restrict__ x2, u16* __restrict__ dst)
{
  const int m = blockIdx.y;
  const float* src = m == 0 ? x0 : (m == 1 ? x1 : x2);
  u16* d = dst + (size_t)m * 4194304;
  const size_t i = ((size_t)blockIdx.x * 256 + threadIdx.x) * 8;
  const float4 a = *reinterpret_cast<const float4*>(src + i);
  const float4 b = *reinterpret_cast<const float4*>(src + i + 4);
  s8 o;
  o[0] = (short)f2bf(a.x); o[1] = (short)f2bf(a.y);
  o[2] = (short)f2bf(a.z); o[3] = (short)f2bf(a.w);
  o[4] = (short)f2bf(b.x); o[5] = (short)f2bf(b.y);
  o[6] = (short)f2bf(b.z); o[7] = (short)f2bf(b.w);
  *reinterpret_cast<s8*>(d + i) = o;
}

// ---------------------------------------------------------------------------
// Weight transposes (fp32 in -> bf16 out), into (n, k) row-major so MFMA
// B-fragments are contiguous 16B loads.
// W_Q/K/V: [h][k=1024][d=64] -> Wt[h*64+d][k].  W_O: [k][m] -> Wt_o[m][k].
// ---------------------------------------------------------------------------
__global__ __launch_bounds__(256) void transpose_qkv(
    const float* __restrict__ wq, const float* __restrict__ wk, const float* __restrict__ wv,
    u16* __restrict__ tq, u16* __restrict__ tk, u16* __restrict__ tv)
{
  __shared__ __align__(16) u16 tile[64 * 65];
  const int mat = blockIdx.z, h = blockIdx.y, kt = blockIdx.x;
  const float* W = mat == 0 ? wq : (mat == 1 ? wk : wv);
  u16*         O = mat == 0 ? tq : (mat == 1 ? tk : tv);
  const float* src = W + (size_t)h * 65536;   // [1024][64]
  u16*         dst = O + (size_t)h * 65536;   // [64][1024]
  const int t = threadIdx.x;
  const int k0 = kt * 64;
  #pragma unroll
  for (int i = 0; i < 16; ++i) {
    int idx = i * 256 + t;
    int kr = idx >> 6, d = idx & 63;
    tile[kr * 65 + d] = f2bf(src[(size_t)(k0 + kr) * 64 + d]);
  }
  __syncthreads();
  #pragma unroll
  for (int i = 0; i < 16; ++i) {
    int idx = i * 256 + t;
    int d = idx >> 6, kr = idx & 63;
    dst[(size_t)d * 1024 + k0 + kr] = tile[kr * 65 + d];
  }
}

__global__ __launch_bounds__(256) void transpose_wo(
    const float* __restrict__ src, u16* __restrict__ dst)
{
  __shared__ __align__(16) u16 tile[64 * 65];
  const int r0 = blockIdx.y * 64, c0 = blockIdx.x * 64;
  const int t = threadIdx.x;
  #pragma unroll
  for (int i = 0; i < 16; ++i) {
    int idx = i * 256 + t;
    int rr = idx >> 6, cc = idx & 63;
    tile[rr * 65 + cc] = f2bf(src[(size_t)(r0 + rr) * 1024 + c0 + cc]);
  }
  __syncthreads();
  #pragma unroll
  for (int i = 0; i < 16; ++i) {
    int idx = i * 256 + t;
    int cc = idx >> 6, rr = idx & 63;
    dst[(size_t)(c0 + cc) * 1024 + r0 + rr] = tile[rr * 65 + cc];
  }
}

// ---------------------------------------------------------------------------
// QKV projection: Xb[4096][1024](bf16) x Wt[64n][1024k] per (proj, head).
// Tile: 64(M) x 64(N) per workgroup, 4 waves stacked in M, BK=32.
// Q,K stored [b][h][pos][64]; V stored TRANSPOSED [b][h][d][pos].
// ---------------------------------------------------------------------------
__global__ __launch_bounds__(256) void qkv_proj(
    const u16* __restrict__ Xb,
    const u16* __restrict__ wtq, const u16* __restrict__ wtk, const u16* __restrict__ wtv,
    const float* __restrict__ bq, const float* __restrict__ bk, const float* __restrict__ bv,
    u16* __restrict__ Qo, u16* __restrict__ Ko, u16* __restrict__ Vto)
{
  constexpr int BST = 40;                      // LDS row stride (shorts): 16B-aligned, ~2-way banks
  __shared__ __align__(16) u16 Bl[64 * BST];
  const int proj = blockIdx.y >> 4;
  const int h    = blockIdx.y & 15;
  const u16* X    = Xb + (size_t)proj * 4194304;
  const u16* Wt   = proj == 0 ? wtq : (proj == 1 ? wtk : wtv);
  const float* bi = proj == 0 ? bq  : (proj == 1 ? bk  : bv);
  const int t = threadIdx.x;
  const int wave = t >> 6, lane = t & 63, lm = lane & 15, quad = lane >> 4;
  const int row0 = blockIdx.x * 64 + wave * 16;
  const u16* Wb = Wt + (size_t)(h * 64) * 1024;
  f4 acc[4] = {f4{0,0,0,0}, f4{0,0,0,0}, f4{0,0,0,0}, f4{0,0,0,0}};
  const int sr = t >> 2, scol = (t & 3) * 8;
  for (int k0 = 0; k0 < 1024; k0 += 32) {
    *reinterpret_cast<s8*>(&Bl[sr * BST + scol]) = ld8(Wb + (size_t)sr * 1024 + k0 + scol);
    __syncthreads();
    s8 a = ld8(X + (size_t)(row0 + lm) * 1024 + k0 + quad * 8);
    #pragma unroll
    for (int nt = 0; nt < 4; ++nt) {
      s8 b = *reinterpret_cast<const s8*>(&Bl[(nt * 16 + lm) * BST + quad * 8]);
      acc[nt] = MFMA16(a, b, acc[nt]);
    }
    __syncthreads();
  }
  const int batch = row0 >> 11;
  const int pos0  = (row0 & 2047) + quad * 4;
  #pragma unroll
  for (int nt = 0; nt < 4; ++nt) {
    const int d = nt * 16 + lm;
    const float bb = bi[h * 64 + d];
    if (proj == 2) {
      s4 pk;
      #pragma unroll
      for (int r = 0; r < 4; ++r) pk[r] = (short)f2bf(acc[nt][r] + bb);
      *reinterpret_cast<s4*>(Vto + ((size_t)((batch * 16 + h) * 64 + d)) * 2048 + pos0) = pk;
    } else {
      u16* O = proj == 0 ? Qo : Ko;
      const size_t base = ((size_t)(batch * 16 + h)) * 2048;
      #pragma unroll
      for (int r = 0; r < 4; ++r)
        O[(base + pos0 + r) * 64 + d] = f2bf(acc[nt][r] + bb);
    }
  }
}

// ---------------------------------------------------------------------------
// Flash attention: one workgroup per (b, h, 64 q-rows); 4 waves x 16 rows.
// K-loop over 64-key tiles, kt <= qt (workgroup-uniform).  Online softmax in
// MFMA C-layout; P round-trips through per-wave LDS to become an A-operand.
// ---------------------------------------------------------------------------
__global__ __launch_bounds__(256) void attn(
    const u16* __restrict__ Q, const u16* __restrict__ K, const u16* __restrict__ Vt,
    const float* __restrict__ amask, u16* __restrict__ Z)
{
  constexpr int PST = 72;                      // 144B stride: 16B-aligned, ~2-way banks
  __shared__ __align__(16) u16 Pl[4 * 16 * PST];
  const int qt = blockIdx.x, h = blockIdx.y, b = blockIdx.z;
  const int t = threadIdx.x, wave = t >> 6, lane = t & 63, lm = lane & 15, quad = lane >> 4;
  const int bh = b * 16 + h;
  const u16* Qb = Q + (size_t)bh * 2048 * 64;
  const u16* Kb = K + (size_t)bh * 2048 * 64;
  const u16* Vb = Vt + (size_t)bh * 64 * 2048;
  const float* mk = amask + b * 2048;
  u16* Pw = &Pl[wave * 16 * PST];
  const int qw0 = qt * 64 + wave * 16;
  const s8 aQ0 = ld8(Qb + (size_t)(qw0 + lm) * 64 + quad * 8);
  const s8 aQ1 = ld8(Qb + (size_t)(qw0 + lm) * 64 + 32 + quad * 8);
  f4 o[4] = {f4{0,0,0,0}, f4{0,0,0,0}, f4{0,0,0,0}, f4{0,0,0,0}};
  float mrow[4], lrow[4];
  int rq[4];
  #pragma unroll
  for (int r = 0; r < 4; ++r) {
    mrow[r] = -__builtin_inff(); lrow[r] = 0.f;
    rq[r] = qw0 + quad * 4 + r;
  }
  for (int kt = 0; kt <= qt; ++kt) {
    const int k0 = kt * 64;
    f4 sc[4] = {f4{0,0,0,0}, f4{0,0,0,0}, f4{0,0,0,0}, f4{0,0,0,0}};
    #pragma unroll
    for (int nt = 0; nt < 4; ++nt) {
      const u16* Kr = Kb + (size_t)(k0 + nt * 16 + lm) * 64;
      sc[nt] = MFMA16(aQ0, ld8(Kr + quad * 8), sc[nt]);
      sc[nt] = MFMA16(aQ1, ld8(Kr + 32 + quad * 8), sc[nt]);
    }
    // scale + causal mask + additive mask; per-row tile max
    float tmax[4] = {-__builtin_inff(), -__builtin_inff(), -__builtin_inff(), -__builtin_inff()};
    #pragma unroll
    for (int nt = 0; nt < 4; ++nt) {
      const int key = k0 + nt * 16 + lm;
      const float mv = mk[key];
      #pragma unroll
      for (int r = 0; r < 4; ++r) {
        float s = (key <= rq[r]) ? sc[nt][r] * 0.125f : -100000.0f;
        s += mv;
        sc[nt][r] = s;
        tmax[r] = fmaxf(tmax[r], s);
      }
    }
    #pragma unroll
    for (int r = 0; r < 4; ++r) {
      #pragma unroll
      for (int off = 1; off < 16; off <<= 1)
        tmax[r] = fmaxf(tmax[r], __shfl_xor(tmax[r], off, 64));
    }
    float alpha[4], rsum[4];
    #pragma unroll
    for (int r = 0; r < 4; ++r) {
      float mn = fmaxf(mrow[r], tmax[r]);
      alpha[r] = __expf(mrow[r] - mn);    // exp(-inf - finite) = 0 on first tile
      mrow[r] = mn;
      rsum[r] = 0.f;
    }
    #pragma unroll
    for (int nt = 0; nt < 4; ++nt) {
      #pragma unroll
      for (int r = 0; r < 4; ++r) {
        float p = __expf(sc[nt][r] - mrow[r]);
        sc[nt][r] = p;
        rsum[r] += p;
      }
    }
    #pragma unroll
    for (int r = 0; r < 4; ++r) {
      #pragma unroll
      for (int off = 1; off < 16; off <<= 1)
        rsum[r] += __shfl_xor(rsum[r], off, 64);
      lrow[r] = lrow[r] * alpha[r] + rsum[r];
    }
    // P (C-layout) -> LDS, rescale O
    #pragma unroll
    for (int nt = 0; nt < 4; ++nt) {
      #pragma unroll
      for (int r = 0; r < 4; ++r)
        Pw[(quad * 4 + r) * PST + nt * 16 + lm] = f2bf(sc[nt][r]);
    }
    #pragma unroll
    for (int nt = 0; nt < 4; ++nt) {
      #pragma unroll
      for (int r = 0; r < 4; ++r)
        o[nt][r] *= alpha[r];
    }
    __syncthreads();
    // PV: P as A-operand from LDS, V^T rows as B-operand from global
    #pragma unroll
    for (int kf = 0; kf < 2; ++kf) {
      s8 aP = *reinterpret_cast<const s8*>(&Pw[lm * PST + kf * 32 + quad * 8]);
      #pragma unroll
      for (int nt = 0; nt < 4; ++nt) {
        s8 bvv = ld8(Vb + (size_t)(nt * 16 + lm) * 2048 + k0 + kf * 32 + quad * 8);
        o[nt] = MFMA16(aP, bvv, o[nt]);
      }
    }
    __syncthreads();
  }
  float inv[4];
  #pragma unroll
  for (int r = 0; r < 4; ++r) inv[r] = 1.0f / lrow[r];
  #pragma unroll
  for (int nt = 0; nt < 4; ++nt) {
    const int col = h * 64 + nt * 16 + lm;
    #pragma unroll
    for (int r = 0; r < 4; ++r)
      Z[((size_t)(b * 2048 + rq[r])) * 1024 + col] = f2bf(o[nt][r] * inv[r]);
  }
}

// ---------------------------------------------------------------------------
// Output projection: Z[4096][1024](bf16) x Wt_o[1024n][1024k] + b_O -> fp32
// ---------------------------------------------------------------------------
__global__ __launch_bounds__(256) void out_proj(
    const u16* __restrict__ Zi, const u16* __restrict__ Wto,
    const float* __restrict__ bO, float* __restrict__ Out)
{
  constexpr int BST = 40;
  __shared__ __align__(16) u16 Bl[64 * BST];
  const int t = threadIdx.x;
  const int wave = t >> 6, lane = t & 63, lm = lane & 15, quad = lane >> 4;
  const int row0 = blockIdx.x * 64 + wave * 16;
  const int nb = blockIdx.y * 64;
  const u16* Wb = Wto + (size_t)nb * 1024;
  f4 acc[4] = {f4{0,0,0,0}, f4{0,0,0,0}, f4{0,0,0,0}, f4{0,0,0,0}};
  const int sr = t >> 2, scol = (t & 3) * 8;
  for (int k0 = 0; k0 < 1024; k0 += 32) {
    *reinterpret_cast<s8*>(&Bl[sr * BST + scol]) = ld8(Wb + (size_t)sr * 1024 + k0 + scol);
    __syncthreads();
    s8 a = ld8(Zi + (size_t)(row0 + lm) * 1024 + k0 + quad * 8);
    #pragma unroll
    for (int nt = 0; nt < 4; ++nt) {
      s8 b = *reinterpret_cast<const s8*>(&Bl[(nt * 16 + lm) * BST + quad * 8]);
      acc[nt] = MFMA16(a, b, acc[nt]);
    }
    __syncthreads();
  }
  #pragma unroll
  for (int nt = 0; nt < 4; ++nt) {
    const int n = nb + nt * 16 + lm;
    const float bb = bO[n];
    #pragma unroll
    for (int r = 0; r < 4; ++r) {
      const int row = row0 + quad * 4 + r;
      Out[(size_t)row * 1024 + n] = acc[nt][r] + bb;
    }
  }
}

// ---------------------------------------------------------------------------
extern "C" void kernel_launch(void* const* d_in, const int* in_sizes, int n_in,
                              void* d_out, int out_size, void* d_ws, size_t ws_size,
                              hipStream_t stream)
{
  const float* xq = (const float*)d_in[0];
  const float* xk = (const float*)d_in[1];
  const float* xv = (const float*)d_in[2];
  const float* am = (const float*)d_in[3];
  const float* wq = (const float*)d_in[4];
  const float* wk = (const float*)d_in[5];
  const float* wv = (const float*)d_in[6];
  const float* wo = (const float*)d_in[7];
  const float* bq = (const float*)d_in[8];
  const float* bk = (const float*)d_in[9];
  const float* bv = (const float*)d_in[10];
  const float* bo = (const float*)d_in[11];
  u16* ws = (u16*)d_ws;
  const size_t M1 = 1u << 20;
  u16* Wtq = ws;              // [1024][1024] bf16
  u16* Wtk = ws + 1 * M1;
  u16* Wtv = ws + 2 * M1;
  u16* Wto = ws + 3 * M1;
  u16* Xb  = ws + 4 * M1;     // 3 x [4096][1024] bf16
  u16* Qw  = ws + 16 * M1;    // [2][16][2048][64] bf16
  u16* Kw  = ws + 20 * M1;    // [2][16][2048][64] bf16
  u16* Vtw = ws + 24 * M1;    // [2][16][64][2048] bf16
  u16* Zw  = ws + 28 * M1;    // [4096][1024] bf16

  cvt_x<<<dim3(2048, 3), 256, 0, stream>>>(xq, xk, xv, Xb);
  transpose_qkv<<<dim3(16, 16, 3), 256, 0, stream>>>(wq, wk, wv, Wtq, Wtk, Wtv);
  transpose_wo<<<dim3(16, 16), 256, 0, stream>>>(wo, Wto);
  qkv_proj<<<dim3(64, 48), 256, 0, stream>>>(Xb, Wtq, Wtk, Wtv,
                                             bq, bk, bv, Qw, Kw, Vtw);
  attn<<<dim3(32, 16, 2), 256, 0, stream>>>(Qw, Kw, Vtw, am, Zw);
  out_proj<<<dim3(64, 16), 256, 0, stream>>>(Zw, Wto, bo, (float*)d_out);
}